// Round 2
// baseline (257.089 us; speedup 1.0000x reference)
//
#include <hip/hip_runtime.h>
#include <hip/hip_bf16.h>

#define B_ 8
#define N_ 1024
#define DIN 256
#define DOUT 256
#define R_ 4

typedef __attribute__((ext_vector_type(8))) short bf16x8;
typedef __attribute__((ext_vector_type(4))) float f32x4;
typedef __attribute__((ext_vector_type(4))) int i32x4;

__device__ __forceinline__ unsigned short f2bf(float f) {
    union { float f; unsigned int u; } v; v.f = f;
    unsigned int u = v.u;
    u += 0x7fffu + ((u >> 16) & 1u);
    return (unsigned short)(u >> 16);
}
__device__ __forceinline__ float bf2f(unsigned short h) {
    union { float f; unsigned int u; } v; v.u = ((unsigned int)h) << 16;
    return v.f;
}

// async global->LDS, 16B/lane. LDS dest = wave-uniform base + lane*16.
__device__ __forceinline__ void gl_lds16(const void* g, void* l) {
    __builtin_amdgcn_global_load_lds(
        (const __attribute__((address_space(1))) unsigned int*)g,
        (__attribute__((address_space(3))) unsigned int*)l, 16, 0, 0);
}

// ---- k0: swizzle rel_w (f32 [R][D][K]) into bf16 MFMA B-fragment layout ----
__global__ __launch_bounds__(256) void k0_swz(const float* __restrict__ rw,
                                              unsigned short* __restrict__ swzW) {
    int t = blockIdx.x * 256 + threadIdx.x;  // 0..32767
    int lane = t & 63, nb = (t >> 6) & 15, ks = (t >> 10) & 7, r = t >> 13;
    int m = lane & 15, q = lane >> 4;
    const float* src = rw + ((r * DOUT + nb * 16 + m) * DIN) + ks * 32 + q * 8;
    float4 v0 = *(const float4*)src;
    float4 v1 = *(const float4*)(src + 4);
    bf16x8 o;
    o[0] = (short)f2bf(v0.x); o[1] = (short)f2bf(v0.y);
    o[2] = (short)f2bf(v0.z); o[3] = (short)f2bf(v0.w);
    o[4] = (short)f2bf(v1.x); o[5] = (short)f2bf(v1.y);
    o[6] = (short)f2bf(v1.z); o[7] = (short)f2bf(v1.w);
    *(bf16x8*)(swzW + (long)t * 8) = o;
}

// ---- k1: G[j][d] = e[j]*(node@rel_w^T + rel_b)[j][d], B-fragment layout -----
// e[j] = exp(sum_d feats[j][d]*attn_w[256+d]); also stores ebf (bf16 e).
__global__ __launch_bounds__(256) void k1_proj(const float* __restrict__ node,
        const unsigned short* __restrict__ swzW, const float* __restrict__ rel_b,
        const float* __restrict__ attn_w,
        unsigned short* __restrict__ fswz, unsigned short* __restrict__ ebf) {
    __shared__ unsigned short Wbuf[2][8192];
    int bid = blockIdx.x;
    int nt = bid & 15, r = (bid >> 4) & 3, b = bid >> 6;
    int w = threadIdx.x >> 6, lane = threadIdx.x & 63;
    int m = lane & 15, q = lane >> 4;
    int n0 = nt * 64 + w * 16;

    const float* Abase = node + ((b * N_ + n0 + m) * DIN) + q * 8;
    const unsigned short* Wsrc = swzW + r * 65536;

#pragma unroll
    for (int i = 0; i < 4; i++)
        gl_lds16(Wsrc + (w * 4 + i) * 512 + lane * 8, &Wbuf[0][(w * 4 + i) * 512]);

    f32x4 acc[16];
#pragma unroll
    for (int i = 0; i < 16; i++) acc[i] = (f32x4)0.0f;

    float4 a0 = *(const float4*)(Abase);
    float4 a1 = *(const float4*)(Abase + 4);

    for (int ks = 0; ks < 8; ks++) {
        int cur = ks & 1;
        __syncthreads();
        if (ks < 7) {
#pragma unroll
            for (int i = 0; i < 4; i++)
                gl_lds16(Wsrc + ((ks + 1) * 16 + w * 4 + i) * 512 + lane * 8,
                         &Wbuf[cur ^ 1][(w * 4 + i) * 512]);
        }
        bf16x8 af;
        af[0] = (short)f2bf(a0.x); af[1] = (short)f2bf(a0.y);
        af[2] = (short)f2bf(a0.z); af[3] = (short)f2bf(a0.w);
        af[4] = (short)f2bf(a1.x); af[5] = (short)f2bf(a1.y);
        af[6] = (short)f2bf(a1.z); af[7] = (short)f2bf(a1.w);
        if (ks < 7) {
            a0 = *(const float4*)(Abase + (ks + 1) * 32);
            a1 = *(const float4*)(Abase + (ks + 1) * 32 + 4);
        }
#pragma unroll
        for (int nb = 0; nb < 16; nb++) {
            bf16x8 wf = *(const bf16x8*)(&Wbuf[cur][nb * 512 + lane * 8]);
            acc[nb] = __builtin_amdgcn_mfma_f32_16x16x32_bf16(af, wf, acc[nb], 0, 0, 0);
        }
    }

    // C layout: row j = n0 + q*4 + reg, col d = nb*16 + m.
    float sj0 = 0.f, sj1 = 0.f, sj2 = 0.f, sj3 = 0.f;
    float bias[16], aw[16];
#pragma unroll
    for (int nb = 0; nb < 16; nb++) {
        int d = nb * 16 + m;
        bias[nb] = rel_b[r * DOUT + d];
        aw[nb] = attn_w[DOUT + d];
        sj0 += (acc[nb][0] + bias[nb]) * aw[nb];
        sj1 += (acc[nb][1] + bias[nb]) * aw[nb];
        sj2 += (acc[nb][2] + bias[nb]) * aw[nb];
        sj3 += (acc[nb][3] + bias[nb]) * aw[nb];
    }
#pragma unroll
    for (int mk = 1; mk <= 8; mk <<= 1) {
        sj0 += __shfl_xor(sj0, mk, 64);
        sj1 += __shfl_xor(sj1, mk, 64);
        sj2 += __shfl_xor(sj2, mk, 64);
        sj3 += __shfl_xor(sj3, mk, 64);
    }
    float e0 = __expf(sj0), e1 = __expf(sj1), e2 = __expf(sj2), e3 = __expf(sj3);

    int slice = b * R_ + r;
    int js = n0 >> 5;
    int jhi = (n0 >> 4) & 1;
    int qp = jhi * 2 + (q >> 1);
    int jj0 = (q & 1) * 4;
    unsigned short* fb = fswz + ((long)(slice * 32 + js) * 16) * 512
                       + qp * 128 + m * 8 + jj0;
#pragma unroll
    for (int nb = 0; nb < 16; nb++) {
        ushort4 o;
        o.x = f2bf((acc[nb][0] + bias[nb]) * e0);
        o.y = f2bf((acc[nb][1] + bias[nb]) * e1);
        o.z = f2bf((acc[nb][2] + bias[nb]) * e2);
        o.w = f2bf((acc[nb][3] + bias[nb]) * e3);
        *(ushort4*)(fb + nb * 512) = o;
    }
    if (m == 0) {
        ushort4 o;
        o.x = f2bf(e0); o.y = f2bf(e1); o.z = f2bf(e2); o.w = f2bf(e3);
        *(ushort4*)(ebf + slice * N_ + n0 + q * 4) = o;
    }
}

// ---- k3: full-j per block, wave-pair step interleave, in-kernel normalize ---
// Block = (slice, 32-row i-tile). Waves {0,1} compute even 32-j steps (rows
// g=0/1), waves {2,3} odd steps (same rows); all 4 waves co-stage each step's
// 16KB G tile (same dbuf/barrier cadence as before -> 4 blocks/CU kept).
// After the loop the pair-sums give the FULL softmax denominator l, so the
// block normalizes and writes bf16 aggN directly (no lbuf, no half combine).
__global__ __launch_bounds__(256, 4) void k3_attn(const int* __restrict__ adj,
        const unsigned short* __restrict__ fswz, const unsigned short* __restrict__ ebf,
        unsigned short* __restrict__ aggN) {
    __shared__ unsigned short Gbuf[2][8192];  // 2 x 16KB
    __shared__ unsigned short Ebuf[1024];     // 2KB: full e table for this slice
    __shared__ float Lx[2][64];               // per-lane l exchange

    int bid = blockIdx.x;
    int slice = (bid & 7) * 4 + ((bid >> 3) & 3);  // XCD-affine slice grouping
    int it = bid >> 5;                             // 0..31 (32-row i-tile)
    int t = threadIdx.x, lane = t & 63, w = t >> 6;
    int m = lane & 15, q = lane >> 4;
    int g = w & 1;    // row group within tile
    int ph = w >> 1;  // step parity this wave computes
    int i0 = it * 32 + g * 16;

    const unsigned short* fsl = fswz + (size_t)slice * (32 * 8192);
    const int* adjbase = adj + (size_t)slice * (N_ * N_)
                       + (size_t)(i0 + m) * N_ + q * 8;
    const unsigned short* esl = ebf + slice * N_;

    // prologue: stage G step 0, full e-table, adj for this wave's first step
#pragma unroll
    for (int i = 0; i < 4; i++)
        gl_lds16(fsl + (w * 4 + i) * 512 + lane * 8, &Gbuf[0][(w * 4 + i) * 512]);
    if (w < 2)
        gl_lds16(esl + w * 512 + lane * 8, &Ebuf[w * 512]);

    i32x4 A0c = *(const i32x4*)(adjbase + ph * 32);
    i32x4 A1c = *(const i32x4*)(adjbase + ph * 32 + 4);

    f32x4 acc[16];
#pragma unroll
    for (int i = 0; i < 16; i++) acc[i] = (f32x4)0.0f;
    float l = 0.f;

    for (int s = 0; s < 32; s++) {
        int cur = s & 1;
        __syncthreads();  // drains staging for step s (and adj prefetch)
        if (s < 31) {
#pragma unroll
            for (int i = 0; i < 4; i++)
                gl_lds16(fsl + (size_t)(s + 1) * 8192 + (w * 4 + i) * 512 + lane * 8,
                         &Gbuf[cur ^ 1][(w * 4 + i) * 512]);
        }
        if ((s & 1) == ph) {
            i32x4 A0n, A1n;
            if (s < 30) {  // prefetch this wave's NEXT step (s+2): 2 steps slack
                A0n = *(const i32x4*)(adjbase + (s + 2) * 32);
                A1n = *(const i32x4*)(adjbase + (s + 2) * 32 + 4);
            }
            bf16x8 ev = *(const bf16x8*)(&Ebuf[s * 32 + q * 8]);
            int av[8] = {A0c.x, A0c.y, A0c.z, A0c.w, A1c.x, A1c.y, A1c.z, A1c.w};
            const int* ei = (const int*)&ev;
            bf16x8 af;
            int* afi = (int*)&af;
#pragma unroll
            for (int p = 0; p < 4; p++) {
                unsigned int msk = (av[2 * p] ? 0xffffu : 0u)
                                 | (av[2 * p + 1] ? 0xffff0000u : 0u);
                afi[p] = (int)(msk & 0x3F803F80u);  // A entries: bf16 1.0 / 0.0
                int me = ei[p] & (int)msk;          // masked e (bf16 pair) for l
                union { int i; float f; } lo, hi;
                lo.i = me << 16;
                hi.i = me & (int)0xffff0000u;
                l += lo.f + hi.f;
            }
            const unsigned short* Gb = &Gbuf[cur][lane * 8];
#pragma unroll
            for (int nb = 0; nb < 16; nb++) {
                bf16x8 bfq = *(const bf16x8*)(Gb + nb * 512);
                acc[nb] = __builtin_amdgcn_mfma_f32_16x16x32_bf16(af, bfq, acc[nb], 0, 0, 0);
            }
            if (s < 30) { A0c = A0n; A1c = A1n; }
        }
    }

    // combine wave pairs (reuse dead Gbuf as f32 exchange buffer)
    __syncthreads();  // all Gbuf reads of step 31 done before overwrite
    if (w >= 2) {
        float* GF = (float*)&Gbuf[0][0];
#pragma unroll
        for (int nb = 0; nb < 16; nb++)
            *(f32x4*)(&GF[g * 4096 + nb * 256 + lane * 4]) = acc[nb];
        Lx[g][lane] = l;
    }
    __syncthreads();
    if (w < 2) {
        const float* GF = (const float*)&Gbuf[0][0];
#pragma unroll
        for (int nb = 0; nb < 16; nb++)
            acc[nb] += *(const f32x4*)(&GF[g * 4096 + nb * 256 + lane * 4]);
        l += Lx[g][lane];
        // full denominator per row m: reduce over q
        l += __shfl_xor(l, 16, 64);
        l += __shfl_xor(l, 32, 64);
        float linv[4];
#pragma unroll
        for (int reg = 0; reg < 4; reg++) {
            float lr = __shfl(l, q * 4 + reg, 64);  // lane r<16 holds row r's l
            linv[reg] = (lr > 0.f) ? 1.0f / lr : 0.f;
        }
        // normalized aggN (bf16): row = i0 + q*4 + reg, col = nb*16 + m
        unsigned short* ob = aggN + ((size_t)(slice * N_ + i0 + q * 4)) * DOUT + m;
#pragma unroll
        for (int nb = 0; nb < 16; nb++) {
#pragma unroll
            for (int reg = 0; reg < 4; reg++)
                ob[(size_t)reg * DOUT + nb * 16] = f2bf(acc[nb][reg] * linv[reg]);
        }
    }
}

// ---- k4: sum normalized per-relation agg, gate, write out -------------------
__global__ __launch_bounds__(256) void k4_out(const unsigned short* __restrict__ aggN,
        const float* __restrict__ gate_w, const float* __restrict__ gate_b,
        float* __restrict__ out) {
    __shared__ float red[4];
    int bid = blockIdx.x;  // 8192 = b*1024 + n
    int n = bid & 1023, b = bid >> 10;
    int d = threadIdx.x;
    float s = 0.f;
#pragma unroll
    for (int r = 0; r < R_; r++)
        s += bf2f(aggN[((size_t)((b * R_ + r) * N_ + n)) * DOUT + d]);
    float v = s * gate_w[d];
#pragma unroll
    for (int off = 32; off; off >>= 1) v += __shfl_down(v, off, 64);
    int lane = d & 63, wave = d >> 6;
    if (lane == 0) red[wave] = v;
    __syncthreads();
    float tot = red[0] + red[1] + red[2] + red[3];
    float g = 1.f / (1.f + __expf(-(tot + gate_b[0])));
    out[((size_t)(b * N_ + n)) * DOUT + d] = g * s;
}

extern "C" void kernel_launch(void* const* d_in, const int* in_sizes, int n_in,
                              void* d_out, int out_size, void* d_ws, size_t ws_size,
                              hipStream_t stream) {
    const float* node   = (const float*)d_in[0];
    const int*   adj    = (const int*)d_in[1];
    const float* rel_w  = (const float*)d_in[2];
    const float* rel_b  = (const float*)d_in[3];
    const float* attn_w = (const float*)d_in[4];
    // d_in[5] = attn_b: cancels in softmax, unused
    const float* gate_w = (const float*)d_in[6];
    const float* gate_b = (const float*)d_in[7];
    float* out = (float*)d_out;

    char* ws = (char*)d_ws;
    unsigned short* swzW = (unsigned short*)ws;                 // 524,288 B
    unsigned short* fswz = (unsigned short*)(ws + 524288);      // 16,777,216 B (G)
    unsigned short* ebf  = (unsigned short*)(ws + 17301504);    // 65,536 B
    unsigned short* aggN = (unsigned short*)(ws + 17367040);    // 16,777,216 B (bf16, normalized)

    k0_swz<<<128, 256, 0, stream>>>(rel_w, swzW);
    k1_proj<<<512, 256, 0, stream>>>(node, swzW, rel_b, attn_w, fswz, ebf);
    k3_attn<<<1024, 256, 0, stream>>>(adj, fswz, ebf, aggN);
    k4_out<<<8192, 256, 0, stream>>>(aggN, gate_w, gate_b, out);
}

// Round 3
// 251.560 us; speedup vs baseline: 1.0220x; 1.0220x over previous
//
#include <hip/hip_runtime.h>
#include <hip/hip_bf16.h>

#define B_ 8
#define N_ 1024
#define DIN 256
#define DOUT 256
#define R_ 4

typedef __attribute__((ext_vector_type(8))) short bf16x8;
typedef __attribute__((ext_vector_type(4))) float f32x4;
typedef __attribute__((ext_vector_type(4))) int i32x4;

__device__ __forceinline__ unsigned short f2bf(float f) {
    union { float f; unsigned int u; } v; v.f = f;
    unsigned int u = v.u;
    u += 0x7fffu + ((u >> 16) & 1u);
    return (unsigned short)(u >> 16);
}
__device__ __forceinline__ float bf2f(unsigned short h) {
    union { float f; unsigned int u; } v; v.u = ((unsigned int)h) << 16;
    return v.f;
}

// async global->LDS, 16B/lane. LDS dest = wave-uniform base + lane*16.
__device__ __forceinline__ void gl_lds16(const void* g, void* l) {
    __builtin_amdgcn_global_load_lds(
        (const __attribute__((address_space(1))) unsigned int*)g,
        (__attribute__((address_space(3))) unsigned int*)l, 16, 0, 0);
}

// raw global 16B load: fixed issue position (exact vmcnt counting), result
// only valid after an explicit s_waitcnt vmcnt(N) (we place those manually).
__device__ __forceinline__ i32x4 gload4(const void* p) {
    i32x4 r;
    asm volatile("global_load_dwordx4 %0, %1, off" : "=v"(r) : "v"(p) : "memory");
    return r;
}

// ---- k0: swizzle rel_w (f32 [R][D][K]) into bf16 MFMA B-fragment layout ----
__global__ __launch_bounds__(256) void k0_swz(const float* __restrict__ rw,
                                              unsigned short* __restrict__ swzW) {
    int t = blockIdx.x * 256 + threadIdx.x;  // 0..32767
    int lane = t & 63, nb = (t >> 6) & 15, ks = (t >> 10) & 7, r = t >> 13;
    int m = lane & 15, q = lane >> 4;
    const float* src = rw + ((r * DOUT + nb * 16 + m) * DIN) + ks * 32 + q * 8;
    float4 v0 = *(const float4*)src;
    float4 v1 = *(const float4*)(src + 4);
    bf16x8 o;
    o[0] = (short)f2bf(v0.x); o[1] = (short)f2bf(v0.y);
    o[2] = (short)f2bf(v0.z); o[3] = (short)f2bf(v0.w);
    o[4] = (short)f2bf(v1.x); o[5] = (short)f2bf(v1.y);
    o[6] = (short)f2bf(v1.z); o[7] = (short)f2bf(v1.w);
    *(bf16x8*)(swzW + (long)t * 8) = o;
}

// ---- k1: G[j][d] = e[j]*(node@rel_w^T + rel_b)[j][d], B-fragment layout -----
// e[j] = exp(sum_d feats[j][d]*attn_w[256+d]); also stores ebf (bf16 e).
__global__ __launch_bounds__(256) void k1_proj(const float* __restrict__ node,
        const unsigned short* __restrict__ swzW, const float* __restrict__ rel_b,
        const float* __restrict__ attn_w,
        unsigned short* __restrict__ fswz, unsigned short* __restrict__ ebf) {
    __shared__ unsigned short Wbuf[2][8192];
    int bid = blockIdx.x;
    int nt = bid & 15, r = (bid >> 4) & 3, b = bid >> 6;
    int w = threadIdx.x >> 6, lane = threadIdx.x & 63;
    int m = lane & 15, q = lane >> 4;
    int n0 = nt * 64 + w * 16;

    const float* Abase = node + ((b * N_ + n0 + m) * DIN) + q * 8;
    const unsigned short* Wsrc = swzW + r * 65536;

#pragma unroll
    for (int i = 0; i < 4; i++)
        gl_lds16(Wsrc + (w * 4 + i) * 512 + lane * 8, &Wbuf[0][(w * 4 + i) * 512]);

    f32x4 acc[16];
#pragma unroll
    for (int i = 0; i < 16; i++) acc[i] = (f32x4)0.0f;

    float4 a0 = *(const float4*)(Abase);
    float4 a1 = *(const float4*)(Abase + 4);

    for (int ks = 0; ks < 8; ks++) {
        int cur = ks & 1;
        __syncthreads();
        if (ks < 7) {
#pragma unroll
            for (int i = 0; i < 4; i++)
                gl_lds16(Wsrc + ((ks + 1) * 16 + w * 4 + i) * 512 + lane * 8,
                         &Wbuf[cur ^ 1][(w * 4 + i) * 512]);
        }
        bf16x8 af;
        af[0] = (short)f2bf(a0.x); af[1] = (short)f2bf(a0.y);
        af[2] = (short)f2bf(a0.z); af[3] = (short)f2bf(a0.w);
        af[4] = (short)f2bf(a1.x); af[5] = (short)f2bf(a1.y);
        af[6] = (short)f2bf(a1.z); af[7] = (short)f2bf(a1.w);
        if (ks < 7) {
            a0 = *(const float4*)(Abase + (ks + 1) * 32);
            a1 = *(const float4*)(Abase + (ks + 1) * 32 + 4);
        }
#pragma unroll
        for (int nb = 0; nb < 16; nb++) {
            bf16x8 wf = *(const bf16x8*)(&Wbuf[cur][nb * 512 + lane * 8]);
            acc[nb] = __builtin_amdgcn_mfma_f32_16x16x32_bf16(af, wf, acc[nb], 0, 0, 0);
        }
    }

    // C layout: row j = n0 + q*4 + reg, col d = nb*16 + m.
    float sj0 = 0.f, sj1 = 0.f, sj2 = 0.f, sj3 = 0.f;
    float bias[16], aw[16];
#pragma unroll
    for (int nb = 0; nb < 16; nb++) {
        int d = nb * 16 + m;
        bias[nb] = rel_b[r * DOUT + d];
        aw[nb] = attn_w[DOUT + d];
        sj0 += (acc[nb][0] + bias[nb]) * aw[nb];
        sj1 += (acc[nb][1] + bias[nb]) * aw[nb];
        sj2 += (acc[nb][2] + bias[nb]) * aw[nb];
        sj3 += (acc[nb][3] + bias[nb]) * aw[nb];
    }
#pragma unroll
    for (int mk = 1; mk <= 8; mk <<= 1) {
        sj0 += __shfl_xor(sj0, mk, 64);
        sj1 += __shfl_xor(sj1, mk, 64);
        sj2 += __shfl_xor(sj2, mk, 64);
        sj3 += __shfl_xor(sj3, mk, 64);
    }
    float e0 = __expf(sj0), e1 = __expf(sj1), e2 = __expf(sj2), e3 = __expf(sj3);

    int slice = b * R_ + r;
    int js = n0 >> 5;
    int jhi = (n0 >> 4) & 1;
    int qp = jhi * 2 + (q >> 1);
    int jj0 = (q & 1) * 4;
    unsigned short* fb = fswz + ((long)(slice * 32 + js) * 16) * 512
                       + qp * 128 + m * 8 + jj0;
#pragma unroll
    for (int nb = 0; nb < 16; nb++) {
        ushort4 o;
        o.x = f2bf((acc[nb][0] + bias[nb]) * e0);
        o.y = f2bf((acc[nb][1] + bias[nb]) * e1);
        o.z = f2bf((acc[nb][2] + bias[nb]) * e2);
        o.w = f2bf((acc[nb][3] + bias[nb]) * e3);
        *(ushort4*)(fb + nb * 512) = o;
    }
    if (m == 0) {
        ushort4 o;
        o.x = f2bf(e0); o.y = f2bf(e1); o.z = f2bf(e2); o.w = f2bf(e3);
        *(ushort4*)(ebf + slice * N_ + n0 + q * 4) = o;
    }
}

// ---- k3 v2: 64-row blocks, all-wave compute, 4-slot ring, counted vmcnt -----
// Block = (slice, 64-row i-tile); wave w owns rows i0=it*64+w*16, full j.
// G tile ring: 4 x 16KB LDS slots, prefetch distance 2. Per step each wave
// issues {4 gl_lds16 + 2 asm adj loads} for step t+2 (6 VMEM ops/group).
// In-order vmcnt retire (m135): at top of step t only group(t+1)=6 ops may
// be in flight -> s_waitcnt vmcnt(6) guarantees group(t) retired BEFORE
// s_barrier (cross-wave LDS visibility). Loads thus span 2 steps; the main
// loop never drains vmcnt to 0 (T3/T4). Raw s_barrier (no compiler vmcnt(0));
// sched_barrier(0) after it pins VALU consumers of asm-loaded adj (rule #18).
// Each wave has the FULL softmax denominator for its rows -> no cross-wave
// combine; normalize in-register and write bf16 aggN.
#define K3_STEP(T_, SLOT_, PFSLOT_, DO_PF_, WAITN_)                            \
  {                                                                            \
    asm volatile("s_waitcnt vmcnt(" #WAITN_ ")" ::: "memory");                 \
    __builtin_amdgcn_s_barrier();                                              \
    __builtin_amdgcn_sched_barrier(0);                                         \
    if (DO_PF_) {                                                              \
      _Pragma("unroll")                                                        \
      for (int i = 0; i < 4; i++)                                              \
        gl_lds16(fsl + (size_t)((T_) + 2) * 8192 + (w * 4 + i) * 512 + lane * 8, \
                 &Gbuf[PFSLOT_][(w * 4 + i) * 512]);                           \
      adjA[PFSLOT_] = gload4(adjbase + ((T_) + 2) * 32);                       \
      adjB[PFSLOT_] = gload4(adjbase + ((T_) + 2) * 32 + 4);                   \
    }                                                                          \
    bf16x8 ev = *(const bf16x8*)(&Ebuf[(T_) * 32 + q * 8]);                    \
    i32x4 A0c = adjA[SLOT_], A1c = adjB[SLOT_];                                \
    int av[8] = {A0c.x, A0c.y, A0c.z, A0c.w, A1c.x, A1c.y, A1c.z, A1c.w};      \
    const int* ei = (const int*)&ev;                                           \
    bf16x8 af; int* afi = (int*)&af;                                           \
    _Pragma("unroll")                                                          \
    for (int p = 0; p < 4; p++) {                                              \
      unsigned int msk = (av[2 * p] ? 0xffffu : 0u)                            \
                       | (av[2 * p + 1] ? 0xffff0000u : 0u);                   \
      afi[p] = (int)(msk & 0x3F803F80u);                                       \
      int me = ei[p] & (int)msk;                                               \
      union { int i; float f; } lo, hi;                                        \
      lo.i = me << 16; hi.i = me & (int)0xffff0000u;                           \
      l += lo.f + hi.f;                                                        \
    }                                                                          \
    const unsigned short* Gb = &Gbuf[SLOT_][lane * 8];                         \
    _Pragma("unroll")                                                          \
    for (int nb = 0; nb < 16; nb++) {                                          \
      bf16x8 bfq = *(const bf16x8*)(Gb + nb * 512);                            \
      acc[nb] = __builtin_amdgcn_mfma_f32_16x16x32_bf16(af, bfq, acc[nb], 0, 0, 0); \
    }                                                                          \
  }

__global__ __launch_bounds__(256, 2) void k3_attn(const int* __restrict__ adj,
        const unsigned short* __restrict__ fswz, const unsigned short* __restrict__ ebf,
        unsigned short* __restrict__ aggN) {
    __shared__ unsigned short Gbuf[4][8192];  // 4 x 16KB ring
    __shared__ unsigned short Ebuf[1024];     // 2KB: full e table for this slice

    int bid = blockIdx.x;  // 512 = 32 slices x 16 i-tiles
    int slice = (bid & 7) * 4 + ((bid >> 3) & 3);  // XCD-affine slice grouping
    int it = bid >> 5;                             // 0..15 (64-row i-tile)
    int t = threadIdx.x, lane = t & 63, w = t >> 6;
    int m = lane & 15, q = lane >> 4;
    int i0 = it * 64 + w * 16;  // this wave's 16 rows

    const unsigned short* fsl = fswz + (size_t)slice * (32 * 8192);
    const int* adjbase = adj + (size_t)slice * (N_ * N_)
                       + (size_t)(i0 + m) * N_ + q * 8;
    const unsigned short* esl = ebf + slice * N_;

    i32x4 adjA[4], adjB[4];

    // prologue, issue order matters for vmcnt counting:
    // [stage(0) x4, ebuf(w<2) x1, adj(0) x2]  then  [stage(1) x4, adj(1) x2]
#pragma unroll
    for (int i = 0; i < 4; i++)
        gl_lds16(fsl + (w * 4 + i) * 512 + lane * 8, &Gbuf[0][(w * 4 + i) * 512]);
    if (w < 2)
        gl_lds16(esl + w * 512 + lane * 8, &Ebuf[w * 512]);
    adjA[0] = gload4(adjbase);
    adjB[0] = gload4(adjbase + 4);
#pragma unroll
    for (int i = 0; i < 4; i++)
        gl_lds16(fsl + 8192 + (w * 4 + i) * 512 + lane * 8, &Gbuf[1][(w * 4 + i) * 512]);
    adjA[1] = gload4(adjbase + 32);
    adjB[1] = gload4(adjbase + 36);

    f32x4 acc[16];
#pragma unroll
    for (int i = 0; i < 16; i++) acc[i] = (f32x4)0.0f;
    float l = 0.f;

    for (int tt = 0; tt < 28; tt += 4) {  // tt multiple of 4 -> slots static
        K3_STEP(tt + 0, 0, 2, 1, 6)
        K3_STEP(tt + 1, 1, 3, 1, 6)
        K3_STEP(tt + 2, 2, 0, 1, 6)
        K3_STEP(tt + 3, 3, 1, 1, 6)
    }
    K3_STEP(28, 0, 2, 1, 6)
    K3_STEP(29, 1, 3, 1, 6)
    K3_STEP(30, 2, 0, 0, 6)
    K3_STEP(31, 3, 1, 0, 0)

    // full denominator per row m: reduce over q (each wave has full j)
    l += __shfl_xor(l, 16, 64);
    l += __shfl_xor(l, 32, 64);
    float linv[4];
#pragma unroll
    for (int reg = 0; reg < 4; reg++) {
        float lr = __shfl(l, q * 4 + reg, 64);  // lane r<16 holds row r's l
        linv[reg] = (lr > 0.f) ? 1.0f / lr : 0.f;
    }
    // normalized aggN (bf16): row = i0 + q*4 + reg, col = nb*16 + m
    unsigned short* ob = aggN + ((size_t)(slice * N_ + i0 + q * 4)) * DOUT + m;
#pragma unroll
    for (int nb = 0; nb < 16; nb++) {
#pragma unroll
        for (int reg = 0; reg < 4; reg++)
            ob[(size_t)reg * DOUT + nb * 16] = f2bf(acc[nb][reg] * linv[reg]);
    }
}

// ---- k4: sum normalized per-relation agg, gate, write out -------------------
__global__ __launch_bounds__(256) void k4_out(const unsigned short* __restrict__ aggN,
        const float* __restrict__ gate_w, const float* __restrict__ gate_b,
        float* __restrict__ out) {
    __shared__ float red[4];
    int bid = blockIdx.x;  // 8192 = b*1024 + n
    int n = bid & 1023, b = bid >> 10;
    int d = threadIdx.x;
    float s = 0.f;
#pragma unroll
    for (int r = 0; r < R_; r++)
        s += bf2f(aggN[((size_t)((b * R_ + r) * N_ + n)) * DOUT + d]);
    float v = s * gate_w[d];
#pragma unroll
    for (int off = 32; off; off >>= 1) v += __shfl_down(v, off, 64);
    int lane = d & 63, wave = d >> 6;
    if (lane == 0) red[wave] = v;
    __syncthreads();
    float tot = red[0] + red[1] + red[2] + red[3];
    float g = 1.f / (1.f + __expf(-(tot + gate_b[0])));
    out[((size_t)(b * N_ + n)) * DOUT + d] = g * s;
}

extern "C" void kernel_launch(void* const* d_in, const int* in_sizes, int n_in,
                              void* d_out, int out_size, void* d_ws, size_t ws_size,
                              hipStream_t stream) {
    const float* node   = (const float*)d_in[0];
    const int*   adj    = (const int*)d_in[1];
    const float* rel_w  = (const float*)d_in[2];
    const float* rel_b  = (const float*)d_in[3];
    const float* attn_w = (const float*)d_in[4];
    // d_in[5] = attn_b: cancels in softmax, unused
    const float* gate_w = (const float*)d_in[6];
    const float* gate_b = (const float*)d_in[7];
    float* out = (float*)d_out;

    char* ws = (char*)d_ws;
    unsigned short* swzW = (unsigned short*)ws;                 // 524,288 B
    unsigned short* fswz = (unsigned short*)(ws + 524288);      // 16,777,216 B (G)
    unsigned short* ebf  = (unsigned short*)(ws + 17301504);    // 65,536 B
    unsigned short* aggN = (unsigned short*)(ws + 17367040);    // 16,777,216 B (bf16, normalized)

    k0_swz<<<128, 256, 0, stream>>>(rel_w, swzW);
    k1_proj<<<512, 256, 0, stream>>>(node, swzW, rel_b, attn_w, fswz, ebf);
    k3_attn<<<512, 256, 0, stream>>>(adj, fswz, ebf, aggN);
    k4_out<<<8192, 256, 0, stream>>>(aggN, gate_w, gate_b, out);
}